// Round 10
// baseline (467.165 us; speedup 1.0000x reference)
//
#include <hip/hip_runtime.h>
#include <float.h>

#define NN 50000
#define NE 800000
#define NG 64
#define CAP 64

typedef __attribute__((ext_vector_type(8))) _Float16 f16x8;
typedef __attribute__((ext_vector_type(4))) float f32x4;
typedef __attribute__((ext_vector_type(4))) _Float16 half4;
typedef __attribute__((ext_vector_type(2))) _Float16 half2v;
typedef unsigned int u32;
typedef unsigned short u16;

// ---------- helpers ----------
__device__ __forceinline__ unsigned f2mono(float f) {
  unsigned b = __float_as_uint(f);
  return (b & 0x80000000u) ? ~b : (b | 0x80000000u);
}
__device__ __forceinline__ float mono2f(unsigned u) {
  unsigned b = (u & 0x80000000u) ? (u & 0x7fffffffu) : ~u;
  return __uint_as_float(b);
}
// async global->LDS 16B DMA (gfx950). LDS dest must be wave-uniform base + lane*16.
__device__ __forceinline__ void gl_lds16(const void* g, void* l) {
  __builtin_amdgcn_global_load_lds((const __attribute__((address_space(1))) u32*)g,
                                   (__attribute__((address_space(3))) u32*)l, 16, 0, 0);
}

// ---------- degree count + ELL fill (ushort cols): 1 edge/thread, max TLP ----------
__global__ void k_count(const int* __restrict__ src, const int* __restrict__ dst,
                        int* __restrict__ cnt, u16* __restrict__ col) {
  int e = blockIdx.x * 256 + threadIdx.x;
  if (e >= NE) return;
  int d = dst[e];
  int s = src[e];
  if ((unsigned)d >= NN || (unsigned)s >= NN) return;
  int pos = atomicAdd(&cnt[d], 1);
  if (pos < CAP) col[d * CAP + pos] = (u16)s;
}

// dinv + pre-scaled input features xs = x * dinv[v]; also zero-init pool buffer
__global__ void k_dinv(const int* __restrict__ cnt, float* __restrict__ dinv,
                       const float* __restrict__ x, float* __restrict__ xs,
                       unsigned* __restrict__ g) {
  int v = blockIdx.x * blockDim.x + threadIdx.x;
  if (v >= NN) return;
  if (v < NG * 256) g[v] = 0u;
  float d = rsqrtf((float)cnt[v] + 1.0f);
  dinv[v] = d;
#pragma unroll
  for (int i = 0; i < 9; ++i) xs[v * 9 + i] = x[v * 9 + i] * d;
}

// ---------- fused weight split+transpose for W2,W3,W4: W[K][Nc] -> Wh/Wl[Nc][K] ----------
__device__ __forceinline__ void splitw1(const float* W, _Float16* Wh, _Float16* Wl,
                                        int i, int K, int Nc) {
  int k = i / Nc, n = i - k * Nc;
  float w = W[i];
  _Float16 h = (_Float16)w;
  _Float16 l = (_Float16)(w - (float)h);
  Wh[(size_t)n * K + k] = h;
  Wl[(size_t)n * K + k] = l;
}
__global__ void k_splitw3(const float* __restrict__ W2, const float* __restrict__ W3,
                          const float* __restrict__ W4,
                          _Float16* __restrict__ W2h, _Float16* __restrict__ W2l,
                          _Float16* __restrict__ W3h, _Float16* __restrict__ W3l,
                          _Float16* __restrict__ W4h, _Float16* __restrict__ W4l) {
  int i = blockIdx.x * 256 + threadIdx.x;
  const int n2 = 128 * 256, n3 = 256 * 256;
  if (i < n2) splitw1(W2, W2h, W2l, i, 128, 256);
  else if (i < n2 + n3) splitw1(W3, W3h, W3l, i - n2, 256, 256);
  else if (i < n2 + 2 * n3) splitw1(W4, W4h, W4l, i - n2 - n3, 256, 256);
}

// ---------- aggregation F=9: 16-lane group per node ----------
__global__ __launch_bounds__(256) void k_agg9(const float* __restrict__ xs,
                                              float* __restrict__ out,
                                              const int* __restrict__ cnt,
                                              const u16* __restrict__ col,
                                              const float* __restrict__ dinv) {
  int v = (blockIdx.x * 256 + threadIdx.x) >> 4;
  int l = threadIdx.x & 15;
  if (v >= NN) return;
  int c = cnt[v]; if (c > CAP) c = CAP;
  const u16* cl = col + (size_t)v * CAP;
  float acc = (l < 9) ? xs[v * 9 + l] : 0.0f;
  int j = 0;
  for (; j + 4 <= c; j += 4) {
    ushort4 u = *(const ushort4*)(cl + j);
    float a0 = (l < 9) ? xs[(int)u.x * 9 + l] : 0.f;
    float a1 = (l < 9) ? xs[(int)u.y * 9 + l] : 0.f;
    float a2 = (l < 9) ? xs[(int)u.z * 9 + l] : 0.f;
    float a3 = (l < 9) ? xs[(int)u.w * 9 + l] : 0.f;
    acc += (a0 + a1) + (a2 + a3);
  }
  for (; j < c; ++j) {
    int u = cl[j];
    if (l < 9) acc += xs[u * 9 + l];
  }
  if (l < 9) out[v * 9 + l] = acc * dinv[v];
}

// ---------- GEMM K=9 -> 128, + bias + relu; writes fp16 (pre-scaled by dinv) ----------
__global__ __launch_bounds__(256) void k_gemm9(const float* __restrict__ in,
                                               const float* __restrict__ W,
                                               const float* __restrict__ bias,
                                               const float* __restrict__ dinv,
                                               _Float16* __restrict__ out) {
  __shared__ float sW[9 * 128];
  __shared__ float sb[128];
  int t = threadIdx.x;
  if (t < 128) sb[t] = bias[t];
  for (int i = t; i < 9 * 128; i += 256) sW[i] = W[i];
  __syncthreads();
  int r = blockIdx.x * 2 + (t >> 7);
  int c = t & 127;
  if (r >= NN) return;
  float acc = sb[c];
#pragma unroll
  for (int i = 0; i < 9; ++i) acc += in[r * 9 + i] * sW[i * 128 + c];
  out[r * 128 + c] = (_Float16)(fmaxf(acc, 0.0f) * dinv[r]);
}

// ---------- aggregation F=128: FOUR nodes per wave (16 loads in flight) ----------
#define G4_128(CL, J, AX, AY) {                          \
    ushort4 u = *(const ushort4*)((CL) + (J));           \
    half2v t0 = h[(size_t)u.x * 64 + lane];              \
    half2v t1 = h[(size_t)u.y * 64 + lane];              \
    half2v t2 = h[(size_t)u.z * 64 + lane];              \
    half2v t3 = h[(size_t)u.w * 64 + lane];              \
    AX += ((float)t0.x + (float)t1.x) + ((float)t2.x + (float)t3.x); \
    AY += ((float)t0.y + (float)t1.y) + ((float)t2.y + (float)t3.y); }
__global__ __launch_bounds__(256) void k_agg128(const half2v* __restrict__ h,
                                                half2v* __restrict__ out,
                                                const int* __restrict__ cnt,
                                                const u16* __restrict__ col,
                                                const float* __restrict__ dinv) {
  int gw = (blockIdx.x * 256 + threadIdx.x) >> 6;
  int lane = threadIdx.x & 63;
  int w0 = gw * 4;
  if (w0 >= NN) return;
  float ax[4], ay[4];
  int c[4];
  const u16* cl[4];
#pragma unroll
  for (int nd = 0; nd < 4; ++nd) {
    int wv = w0 + nd;
    half2v s = h[(size_t)wv * 64 + lane];
    ax[nd] = (float)s.x; ay[nd] = (float)s.y;
    int cc = cnt[wv]; if (cc > CAP) cc = CAP;
    c[nd] = cc;
    cl[nd] = col + (size_t)wv * CAP;
  }
  int mc = min(min(c[0], c[1]), min(c[2], c[3]));
  int j = 0;
  for (; j + 4 <= mc; j += 4) {
#pragma unroll
    for (int nd = 0; nd < 4; ++nd) G4_128(cl[nd], j, ax[nd], ay[nd]);
  }
#pragma unroll
  for (int nd = 0; nd < 4; ++nd) {
    int jj = j;
    for (; jj + 4 <= c[nd]; jj += 4) G4_128(cl[nd], jj, ax[nd], ay[nd]);
    for (; jj < c[nd]; ++jj) {
      half2v tv = h[(size_t)cl[nd][jj] * 64 + lane];
      ax[nd] += (float)tv.x; ay[nd] += (float)tv.y;
    }
    float d = dinv[w0 + nd];
    half2v o;
    o.x = (_Float16)(ax[nd] * d); o.y = (_Float16)(ay[nd] * d);
    out[(size_t)(w0 + nd) * 64 + lane] = o;
  }
}

// ---------- aggregation F=256: FOUR nodes per wave (16 loads in flight) ----------
#define G4_256(CL, J, AX, AY, AZ, AW) {                  \
    ushort4 u = *(const ushort4*)((CL) + (J));           \
    half4 t0 = h[(size_t)u.x * 64 + lane];               \
    half4 t1 = h[(size_t)u.y * 64 + lane];               \
    half4 t2 = h[(size_t)u.z * 64 + lane];               \
    half4 t3 = h[(size_t)u.w * 64 + lane];               \
    AX += ((float)t0.x + (float)t1.x) + ((float)t2.x + (float)t3.x); \
    AY += ((float)t0.y + (float)t1.y) + ((float)t2.y + (float)t3.y); \
    AZ += ((float)t0.z + (float)t1.z) + ((float)t2.z + (float)t3.z); \
    AW += ((float)t0.w + (float)t1.w) + ((float)t2.w + (float)t3.w); }
__global__ __launch_bounds__(256) void k_agg256(const half4* __restrict__ h,
                                                half4* __restrict__ out,
                                                const int* __restrict__ cnt,
                                                const u16* __restrict__ col,
                                                const float* __restrict__ dinv) {
  int gw = (blockIdx.x * 256 + threadIdx.x) >> 6;
  int lane = threadIdx.x & 63;
  int w0 = gw * 4;
  if (w0 >= NN) return;
  float ax[4], ay[4], az[4], aw[4];
  int c[4];
  const u16* cl[4];
#pragma unroll
  for (int nd = 0; nd < 4; ++nd) {
    int wv = w0 + nd;
    half4 s = h[(size_t)wv * 64 + lane];
    ax[nd] = (float)s.x; ay[nd] = (float)s.y; az[nd] = (float)s.z; aw[nd] = (float)s.w;
    int cc = cnt[wv]; if (cc > CAP) cc = CAP;
    c[nd] = cc;
    cl[nd] = col + (size_t)wv * CAP;
  }
  int mc = min(min(c[0], c[1]), min(c[2], c[3]));
  int j = 0;
  for (; j + 4 <= mc; j += 4) {
#pragma unroll
    for (int nd = 0; nd < 4; ++nd) G4_256(cl[nd], j, ax[nd], ay[nd], az[nd], aw[nd]);
  }
#pragma unroll
  for (int nd = 0; nd < 4; ++nd) {
    int jj = j;
    for (; jj + 4 <= c[nd]; jj += 4) G4_256(cl[nd], jj, ax[nd], ay[nd], az[nd], aw[nd]);
    for (; jj < c[nd]; ++jj) {
      half4 tv = h[(size_t)cl[nd][jj] * 64 + lane];
      ax[nd] += (float)tv.x; ay[nd] += (float)tv.y;
      az[nd] += (float)tv.z; aw[nd] += (float)tv.w;
    }
    float d = dinv[w0 + nd];
    half4 o;
    o.x = (_Float16)(ax[nd] * d); o.y = (_Float16)(ay[nd] * d);
    o.z = (_Float16)(az[nd] * d); o.w = (_Float16)(aw[nd] * d);
    out[(size_t)(w0 + nd) * 64 + lane] = o;
  }
}

// ---------- MFMA fp16 hi/lo-weight GEMM, DMA LDS staging (m97 structure) ----------
__global__ __launch_bounds__(256) void k_mm(const _Float16* __restrict__ A,
                                            const _Float16* __restrict__ Bh,
                                            const _Float16* __restrict__ Bl,
                                            const float* __restrict__ bias,
                                            _Float16* __restrict__ C,
                                            const float* __restrict__ dinv,
                                            const int* __restrict__ batch,
                                            unsigned* __restrict__ gpool,
                                            int M, int K, int Nc, int mode) {
  __shared__ __align__(16) _Float16 Alds[128 * 64];   // 16 KB
  __shared__ __align__(16) _Float16 Bhl[128 * 64];    // 16 KB
  __shared__ __align__(16) _Float16 Bll[128 * 64];    // 16 KB
  int t = threadIdx.x;
  int wave = t >> 6, lane = t & 63;
  int wm = wave & 1, wn = wave >> 1;
  int rowBase = blockIdx.x * 128;
  int colBase = blockIdx.y * 128;
  int lm = lane & 15;
  int q  = lane >> 4;

  int srl = wave * 32 + (lane >> 3);
  int sj  = lane & 7;
  int ssw = lane >> 3;
  int gseg = sj ^ ssw;

  f32x4 acc[4][4];
#pragma unroll
  for (int i = 0; i < 4; ++i)
#pragma unroll
    for (int j = 0; j < 4; ++j) acc[i][j] = (f32x4){0.f, 0.f, 0.f, 0.f};

  int nit = K >> 6;
  for (int it = 0; it < nit; ++it) {
    __syncthreads();
#pragma unroll
    for (int c = 0; c < 4; ++c) {
      int rl = srl + c * 8;
      int ga = rowBase + rl; if (ga > M - 1) ga = M - 1;
      int gb = colBase + rl;
      unsigned off = (unsigned)it * 64 + gseg * 8;
      int ldst = (wave * 32 + c * 8) * 64 + lane * 8;
      gl_lds16(A  + (size_t)ga * K + off, Alds + ldst);
      gl_lds16(Bh + (size_t)gb * K + off, Bhl + ldst);
      gl_lds16(Bl + (size_t)gb * K + off, Bll + ldst);
    }
    __syncthreads();

#pragma unroll
    for (int s2 = 0; s2 < 2; ++s2) {
      int slotq = ((s2 << 2) | q);
      f16x8 vbh[4], vbl[4];
#pragma unroll
      for (int ni = 0; ni < 4; ++ni) {
        int rB = wn * 64 + ni * 16 + lm;
        int slot = slotq ^ (lm & 7);
        vbh[ni] = *(const f16x8*)(Bhl + rB * 64 + slot * 8);
        vbl[ni] = *(const f16x8*)(Bll + rB * 64 + slot * 8);
      }
#pragma unroll
      for (int mi = 0; mi < 4; ++mi) {
        int rA = wm * 64 + mi * 16 + lm;
        int slot = slotq ^ (lm & 7);
        f16x8 va = *(const f16x8*)(Alds + rA * 64 + slot * 8);
#pragma unroll
        for (int ni = 0; ni < 4; ++ni) {
          acc[mi][ni] = __builtin_amdgcn_mfma_f32_16x16x32_f16(va, vbh[ni], acc[mi][ni], 0, 0, 0);
          acc[mi][ni] = __builtin_amdgcn_mfma_f32_16x16x32_f16(va, vbl[ni], acc[mi][ni], 0, 0, 0);
        }
      }
    }
  }

  int rowOff = (lane >> 4) * 4;
  if (mode == 2) {
    __syncthreads();
    unsigned* ldsPool = (unsigned*)Alds;
    for (int i = t; i < 4 * 256; i += 256) ldsPool[i] = 0u;
    __syncthreads();
    int b0 = batch[rowBase];
#pragma unroll
    for (int mi = 0; mi < 4; ++mi) {
#pragma unroll
      for (int ni = 0; ni < 4; ++ni) {
        int gc = colBase + wn * 64 + ni * 16 + lm;
        float bsv = bias[gc];
#pragma unroll
        for (int r = 0; r < 4; ++r) {
          int gr = rowBase + wm * 64 + mi * 16 + rowOff + r;
          if (gr < M) {
            float v = acc[mi][ni][r] + bsv;
            int idx = batch[gr] - b0;
            if (idx < 0) idx = 0;
            if (idx > 3) idx = 3;
            atomicMax(&ldsPool[idx * 256 + gc], f2mono(v));
          }
        }
      }
    }
    __syncthreads();
#pragma unroll
    for (int s4 = 0; s4 < 4; ++s4) {
      unsigned mv = ldsPool[s4 * 256 + t];
      int gb = b0 + s4;
      if (mv && gb < NG) atomicMax(&gpool[gb * 256 + t], mv);
    }
  } else {
#pragma unroll
    for (int mi = 0; mi < 4; ++mi) {
#pragma unroll
      for (int ni = 0; ni < 4; ++ni) {
        int gc = colBase + wn * 64 + ni * 16 + lm;
        float bsv = bias[gc];
#pragma unroll
        for (int r = 0; r < 4; ++r) {
          int gr = rowBase + wm * 64 + mi * 16 + rowOff + r;
          if (gr < M) {
            float v = fmaxf(acc[mi][ni][r] + bsv, 0.0f);
            C[(size_t)gr * Nc + gc] = (_Float16)(v * dinv[gr]);
          }
        }
      }
    }
  }
}

// ---------- dense head ----------
__global__ __launch_bounds__(256) void k_head(const unsigned* __restrict__ g,
                                              const float* __restrict__ Wl2, const float* __restrict__ bl2,
                                              const float* __restrict__ Wl3, const float* __restrict__ bl3,
                                              const float* __restrict__ Wl, const float* __restrict__ bl,
                                              float* __restrict__ out) {
  __shared__ float s0[256];
  __shared__ float s1[128];
  __shared__ float s2[128];
  int b = blockIdx.x, t = threadIdx.x;
  s0[t] = mono2f(g[b * 256 + t]);
  __syncthreads();
  if (t < 128) {
    float acc = bl2[t];
    for (int k = 0; k < 256; ++k) acc += s0[k] * Wl2[k * 128 + t];
    s1[t] = fmaxf(acc, 0.0f);
  }
  __syncthreads();
  if (t < 128) {
    float acc = bl3[t];
    for (int k = 0; k < 128; ++k) acc += s1[k] * Wl3[k * 128 + t];
    s2[t] = fmaxf(acc, 0.0f);
  }
  __syncthreads();
  if (t < 10) {
    float acc = bl[t];
    for (int k = 0; k < 128; ++k) acc += s2[k] * Wl[k * 10 + t];
    out[b * 10 + t] = acc;
  }
}

extern "C" void kernel_launch(void* const* d_in, const int* in_sizes, int n_in,
                              void* d_out, int out_size, void* d_ws, size_t ws_size,
                              hipStream_t stream) {
  const float* x   = (const float*)d_in[0];
  const int* eidx  = (const int*)d_in[1];
  const int* batch = (const int*)d_in[2];
  const float* W1 = (const float*)d_in[3];   const float* b1 = (const float*)d_in[4];
  const float* W2 = (const float*)d_in[5];   const float* b2 = (const float*)d_in[6];
  const float* W3 = (const float*)d_in[7];   const float* b3 = (const float*)d_in[8];
  const float* W4 = (const float*)d_in[9];   const float* b4 = (const float*)d_in[10];
  const float* Wl2 = (const float*)d_in[11]; const float* bl2 = (const float*)d_in[12];
  const float* Wl3 = (const float*)d_in[13]; const float* bl3 = (const float*)d_in[14];
  const float* Wl  = (const float*)d_in[15]; const float* bl  = (const float*)d_in[16];
  float* out = (float*)d_out;

  // ---- workspace carve ----
  _Float16* bufA = (_Float16*)d_ws;                                // NN*256 fp16
  _Float16* bufB = bufA + (size_t)NN * 256;                        // NN*256 fp16
  int* cnt  = (int*)(bufB + (size_t)NN * 256);                     // NN
  float* dinv = (float*)(cnt + NN);                                // NN
  u16* col  = (u16*)(dinv + NN);                                   // NN*CAP ushort
  unsigned* g = (unsigned*)(col + (size_t)NN * CAP);               // NG*256
  _Float16* W2h = (_Float16*)(g + NG * 256);                       // 256*128
  _Float16* W2l = W2h + 256 * 128;
  _Float16* W3h = W2l + 256 * 128;                                 // 256*256
  _Float16* W3l = W3h + 256 * 256;
  _Float16* W4h = W3l + 256 * 256;
  _Float16* W4l = W4h + 256 * 256;
  float* xs = (float*)bufA;        // NN*9 fp32, dead before k_gemm9 writes bufA
  float* agg9out = (float*)bufB;   // NN*9 fp32, dead before k_agg128 writes bufB

  const int* src = eidx;
  const int* dst = eidx + NE;

  hipMemsetAsync(cnt, 0, NN * sizeof(int), stream);

  k_count<<<(NE + 255) / 256, 256, 0, stream>>>(src, dst, cnt, col);
  k_dinv<<<(NN + 255) / 256, 256, 0, stream>>>(cnt, dinv, x, xs, g);

  k_splitw3<<<(128 * 256 + 2 * 256 * 256 + 255) / 256, 256, 0, stream>>>(
      W2, W3, W4, W2h, W2l, W3h, W3l, W4h, W4l);

  // layer 1: agg 9-dim fp32, GEMM 9->128 (+relu, *dinv, fp16 out to bufA)
  k_agg9<<<(NN + 15) / 16, 256, 0, stream>>>(xs, agg9out, cnt, col, dinv);
  k_gemm9<<<NN / 2, 256, 0, stream>>>(agg9out, W1, b1, dinv, bufA);

  dim3 gmm((NN + 127) / 128, 2);
  int aggGrid = ((NN + 3) / 4 * 64 + 255) / 256;   // four nodes per wave

  // layer 2: gather 128-dim bufA->bufB, MFMA GEMM 128->256 bufB->bufA
  k_agg128<<<aggGrid, 256, 0, stream>>>((const half2v*)bufA, (half2v*)bufB, cnt, col, dinv);
  k_mm<<<gmm, 256, 0, stream>>>(bufB, W2h, W2l, b2, bufA, dinv, batch, g, NN, 128, 256, 1);

  // layer 3: gather 256-dim bufA->bufB, GEMM bufB->bufA
  k_agg256<<<aggGrid, 256, 0, stream>>>((const half4*)bufA, (half4*)bufB, cnt, col, dinv);
  k_mm<<<gmm, 256, 0, stream>>>(bufB, W3h, W3l, b3, bufA, dinv, batch, g, NN, 256, 256, 1);

  // layer 4: gather 256-dim bufA->bufB, GEMM + fused max-pool (no C write)
  k_agg256<<<aggGrid, 256, 0, stream>>>((const half4*)bufA, (half4*)bufB, cnt, col, dinv);
  k_mm<<<gmm, 256, 0, stream>>>(bufB, W4h, W4l, b4, bufA, dinv, batch, g, NN, 256, 256, 2);

  // head
  k_head<<<NG, 256, 0, stream>>>(g, Wl2, bl2, Wl3, bl3, Wl, bl, out);
}

// Round 11
// 447.027 us; speedup vs baseline: 1.0450x; 1.0450x over previous
//
#include <hip/hip_runtime.h>
#include <float.h>

#define NN 50000
#define NE 800000
#define NG 64
#define CAP 64

typedef __attribute__((ext_vector_type(8))) _Float16 f16x8;
typedef __attribute__((ext_vector_type(4))) float f32x4;
typedef __attribute__((ext_vector_type(4))) _Float16 half4;
typedef __attribute__((ext_vector_type(2))) _Float16 half2v;
typedef unsigned int u32;
typedef unsigned short u16;

// ---------- helpers ----------
__device__ __forceinline__ unsigned f2mono(float f) {
  unsigned b = __float_as_uint(f);
  return (b & 0x80000000u) ? ~b : (b | 0x80000000u);
}
__device__ __forceinline__ float mono2f(unsigned u) {
  unsigned b = (u & 0x80000000u) ? (u & 0x7fffffffu) : ~u;
  return __uint_as_float(b);
}
// async global->LDS 16B DMA (gfx950). LDS dest must be wave-uniform base + lane*16.
__device__ __forceinline__ void gl_lds16(const void* g, void* l) {
  __builtin_amdgcn_global_load_lds((const __attribute__((address_space(1))) u32*)g,
                                   (__attribute__((address_space(3))) u32*)l, 16, 0, 0);
}

// ---------- degree count + ELL fill (ushort cols): 1 edge/thread, max TLP ----------
__global__ void k_count(const int* __restrict__ src, const int* __restrict__ dst,
                        int* __restrict__ cnt, u16* __restrict__ col) {
  int e = blockIdx.x * 256 + threadIdx.x;
  if (e >= NE) return;
  int d = dst[e];
  int s = src[e];
  if ((unsigned)d >= NN || (unsigned)s >= NN) return;
  int pos = atomicAdd(&cnt[d], 1);
  if (pos < CAP) col[d * CAP + pos] = (u16)s;
}

// dinv + pre-scaled input features xs = x * dinv[v]; also zero-init pool buffer
__global__ void k_dinv(const int* __restrict__ cnt, float* __restrict__ dinv,
                       const float* __restrict__ x, float* __restrict__ xs,
                       unsigned* __restrict__ g) {
  int v = blockIdx.x * blockDim.x + threadIdx.x;
  if (v >= NN) return;
  if (v < NG * 256) g[v] = 0u;
  float d = rsqrtf((float)cnt[v] + 1.0f);
  dinv[v] = d;
#pragma unroll
  for (int i = 0; i < 9; ++i) xs[v * 9 + i] = x[v * 9 + i] * d;
}

// ---------- fused weight split+transpose for W2,W3,W4: W[K][Nc] -> Wh/Wl[Nc][K] ----------
__device__ __forceinline__ void splitw1(const float* W, _Float16* Wh, _Float16* Wl,
                                        int i, int K, int Nc) {
  int k = i / Nc, n = i - k * Nc;
  float w = W[i];
  _Float16 h = (_Float16)w;
  _Float16 l = (_Float16)(w - (float)h);
  Wh[(size_t)n * K + k] = h;
  Wl[(size_t)n * K + k] = l;
}
__global__ void k_splitw3(const float* __restrict__ W2, const float* __restrict__ W3,
                          const float* __restrict__ W4,
                          _Float16* __restrict__ W2h, _Float16* __restrict__ W2l,
                          _Float16* __restrict__ W3h, _Float16* __restrict__ W3l,
                          _Float16* __restrict__ W4h, _Float16* __restrict__ W4l) {
  int i = blockIdx.x * 256 + threadIdx.x;
  const int n2 = 128 * 256, n3 = 256 * 256;
  if (i < n2) splitw1(W2, W2h, W2l, i, 128, 256);
  else if (i < n2 + n3) splitw1(W3, W3h, W3l, i - n2, 256, 256);
  else if (i < n2 + 2 * n3) splitw1(W4, W4h, W4l, i - n2 - n3, 256, 256);
}

// ---------- aggregation F=9: 16-lane group per node ----------
__global__ __launch_bounds__(256) void k_agg9(const float* __restrict__ xs,
                                              float* __restrict__ out,
                                              const int* __restrict__ cnt,
                                              const u16* __restrict__ col,
                                              const float* __restrict__ dinv) {
  int v = (blockIdx.x * 256 + threadIdx.x) >> 4;
  int l = threadIdx.x & 15;
  if (v >= NN) return;
  int c = cnt[v]; if (c > CAP) c = CAP;
  const u16* cl = col + (size_t)v * CAP;
  float acc = (l < 9) ? xs[v * 9 + l] : 0.0f;
  int j = 0;
  for (; j + 4 <= c; j += 4) {
    ushort4 u = *(const ushort4*)(cl + j);
    float a0 = (l < 9) ? xs[(int)u.x * 9 + l] : 0.f;
    float a1 = (l < 9) ? xs[(int)u.y * 9 + l] : 0.f;
    float a2 = (l < 9) ? xs[(int)u.z * 9 + l] : 0.f;
    float a3 = (l < 9) ? xs[(int)u.w * 9 + l] : 0.f;
    acc += (a0 + a1) + (a2 + a3);
  }
  for (; j < c; ++j) {
    int u = cl[j];
    if (l < 9) acc += xs[u * 9 + l];
  }
  if (l < 9) out[v * 9 + l] = acc * dinv[v];
}

// ---------- GEMM K=9 -> 128, + bias + relu; writes fp16 (pre-scaled by dinv) ----------
__global__ __launch_bounds__(256) void k_gemm9(const float* __restrict__ in,
                                               const float* __restrict__ W,
                                               const float* __restrict__ bias,
                                               const float* __restrict__ dinv,
                                               _Float16* __restrict__ out) {
  __shared__ float sW[9 * 128];
  __shared__ float sb[128];
  int t = threadIdx.x;
  if (t < 128) sb[t] = bias[t];
  for (int i = t; i < 9 * 128; i += 256) sW[i] = W[i];
  __syncthreads();
  int r = blockIdx.x * 2 + (t >> 7);
  int c = t & 127;
  if (r >= NN) return;
  float acc = sb[c];
#pragma unroll
  for (int i = 0; i < 9; ++i) acc += in[r * 9 + i] * sW[i * 128 + c];
  out[r * 128 + c] = (_Float16)(fmaxf(acc, 0.0f) * dinv[r]);
}

// ---------- aggregation F=128: TWO nodes per wave (8 loads in flight) ----------
__global__ __launch_bounds__(256) void k_agg128(const half2v* __restrict__ h,
                                                half2v* __restrict__ out,
                                                const int* __restrict__ cnt,
                                                const u16* __restrict__ col,
                                                const float* __restrict__ dinv) {
  int gw = (blockIdx.x * 256 + threadIdx.x) >> 6;
  int lane = threadIdx.x & 63;
  int w0 = gw * 2, w1 = w0 + 1;
  if (w0 >= NN) return;
  half2v s0 = h[(size_t)w0 * 64 + lane];
  half2v s1 = h[(size_t)w1 * 64 + lane];
  float a0x = (float)s0.x, a0y = (float)s0.y;
  float a1x = (float)s1.x, a1y = (float)s1.y;
  int c0 = cnt[w0]; if (c0 > CAP) c0 = CAP;
  int c1 = cnt[w1]; if (c1 > CAP) c1 = CAP;
  const u16* cl0 = col + (size_t)w0 * CAP;
  const u16* cl1 = col + (size_t)w1 * CAP;
  int j0 = 0, j1 = 0;
  while (j0 + 4 <= c0 && j1 + 4 <= c1) {
    ushort4 u0 = *(const ushort4*)(cl0 + j0);
    ushort4 u1 = *(const ushort4*)(cl1 + j1);
    half2v t00 = h[(size_t)u0.x * 64 + lane];
    half2v t01 = h[(size_t)u0.y * 64 + lane];
    half2v t02 = h[(size_t)u0.z * 64 + lane];
    half2v t03 = h[(size_t)u0.w * 64 + lane];
    half2v t10 = h[(size_t)u1.x * 64 + lane];
    half2v t11 = h[(size_t)u1.y * 64 + lane];
    half2v t12 = h[(size_t)u1.z * 64 + lane];
    half2v t13 = h[(size_t)u1.w * 64 + lane];
    a0x += ((float)t00.x + (float)t01.x) + ((float)t02.x + (float)t03.x);
    a0y += ((float)t00.y + (float)t01.y) + ((float)t02.y + (float)t03.y);
    a1x += ((float)t10.x + (float)t11.x) + ((float)t12.x + (float)t13.x);
    a1y += ((float)t10.y + (float)t11.y) + ((float)t12.y + (float)t13.y);
    j0 += 4; j1 += 4;
  }
  for (; j0 + 4 <= c0; j0 += 4) {
    ushort4 u = *(const ushort4*)(cl0 + j0);
    half2v t0 = h[(size_t)u.x * 64 + lane];
    half2v t1 = h[(size_t)u.y * 64 + lane];
    half2v t2 = h[(size_t)u.z * 64 + lane];
    half2v t3 = h[(size_t)u.w * 64 + lane];
    a0x += ((float)t0.x + (float)t1.x) + ((float)t2.x + (float)t3.x);
    a0y += ((float)t0.y + (float)t1.y) + ((float)t2.y + (float)t3.y);
  }
  for (; j1 + 4 <= c1; j1 += 4) {
    ushort4 u = *(const ushort4*)(cl1 + j1);
    half2v t0 = h[(size_t)u.x * 64 + lane];
    half2v t1 = h[(size_t)u.y * 64 + lane];
    half2v t2 = h[(size_t)u.z * 64 + lane];
    half2v t3 = h[(size_t)u.w * 64 + lane];
    a1x += ((float)t0.x + (float)t1.x) + ((float)t2.x + (float)t3.x);
    a1y += ((float)t0.y + (float)t1.y) + ((float)t2.y + (float)t3.y);
  }
  for (; j0 < c0; ++j0) {
    half2v tv = h[(size_t)cl0[j0] * 64 + lane];
    a0x += (float)tv.x; a0y += (float)tv.y;
  }
  for (; j1 < c1; ++j1) {
    half2v tv = h[(size_t)cl1[j1] * 64 + lane];
    a1x += (float)tv.x; a1y += (float)tv.y;
  }
  float d0 = dinv[w0], d1 = dinv[w1];
  half2v o0, o1;
  o0.x = (_Float16)(a0x * d0); o0.y = (_Float16)(a0y * d0);
  o1.x = (_Float16)(a1x * d1); o1.y = (_Float16)(a1y * d1);
  out[(size_t)w0 * 64 + lane] = o0;
  out[(size_t)w1 * 64 + lane] = o1;
}

// ---------- aggregation F=256: TWO nodes per wave (8 loads in flight) ----------
__global__ __launch_bounds__(256) void k_agg256(const half4* __restrict__ h,
                                                half4* __restrict__ out,
                                                const int* __restrict__ cnt,
                                                const u16* __restrict__ col,
                                                const float* __restrict__ dinv) {
  int gw = (blockIdx.x * 256 + threadIdx.x) >> 6;
  int lane = threadIdx.x & 63;
  int w0 = gw * 2, w1 = w0 + 1;
  if (w0 >= NN) return;
  half4 s0 = h[(size_t)w0 * 64 + lane];
  half4 s1 = h[(size_t)w1 * 64 + lane];
  float a0x = (float)s0.x, a0y = (float)s0.y, a0z = (float)s0.z, a0w = (float)s0.w;
  float a1x = (float)s1.x, a1y = (float)s1.y, a1z = (float)s1.z, a1w = (float)s1.w;
  int c0 = cnt[w0]; if (c0 > CAP) c0 = CAP;
  int c1 = cnt[w1]; if (c1 > CAP) c1 = CAP;
  const u16* cl0 = col + (size_t)w0 * CAP;
  const u16* cl1 = col + (size_t)w1 * CAP;
  int j0 = 0, j1 = 0;
  while (j0 + 4 <= c0 && j1 + 4 <= c1) {
    ushort4 u0 = *(const ushort4*)(cl0 + j0);
    ushort4 u1 = *(const ushort4*)(cl1 + j1);
    half4 t00 = h[(size_t)u0.x * 64 + lane];
    half4 t01 = h[(size_t)u0.y * 64 + lane];
    half4 t02 = h[(size_t)u0.z * 64 + lane];
    half4 t03 = h[(size_t)u0.w * 64 + lane];
    half4 t10 = h[(size_t)u1.x * 64 + lane];
    half4 t11 = h[(size_t)u1.y * 64 + lane];
    half4 t12 = h[(size_t)u1.z * 64 + lane];
    half4 t13 = h[(size_t)u1.w * 64 + lane];
    a0x += ((float)t00.x + (float)t01.x) + ((float)t02.x + (float)t03.x);
    a0y += ((float)t00.y + (float)t01.y) + ((float)t02.y + (float)t03.y);
    a0z += ((float)t00.z + (float)t01.z) + ((float)t02.z + (float)t03.z);
    a0w += ((float)t00.w + (float)t01.w) + ((float)t02.w + (float)t03.w);
    a1x += ((float)t10.x + (float)t11.x) + ((float)t12.x + (float)t13.x);
    a1y += ((float)t10.y + (float)t11.y) + ((float)t12.y + (float)t13.y);
    a1z += ((float)t10.z + (float)t11.z) + ((float)t12.z + (float)t13.z);
    a1w += ((float)t10.w + (float)t11.w) + ((float)t12.w + (float)t13.w);
    j0 += 4; j1 += 4;
  }
  for (; j0 + 4 <= c0; j0 += 4) {
    ushort4 u = *(const ushort4*)(cl0 + j0);
    half4 t0 = h[(size_t)u.x * 64 + lane];
    half4 t1 = h[(size_t)u.y * 64 + lane];
    half4 t2 = h[(size_t)u.z * 64 + lane];
    half4 t3 = h[(size_t)u.w * 64 + lane];
    a0x += ((float)t0.x + (float)t1.x) + ((float)t2.x + (float)t3.x);
    a0y += ((float)t0.y + (float)t1.y) + ((float)t2.y + (float)t3.y);
    a0z += ((float)t0.z + (float)t1.z) + ((float)t2.z + (float)t3.z);
    a0w += ((float)t0.w + (float)t1.w) + ((float)t2.w + (float)t3.w);
  }
  for (; j1 + 4 <= c1; j1 += 4) {
    ushort4 u = *(const ushort4*)(cl1 + j1);
    half4 t0 = h[(size_t)u.x * 64 + lane];
    half4 t1 = h[(size_t)u.y * 64 + lane];
    half4 t2 = h[(size_t)u.z * 64 + lane];
    half4 t3 = h[(size_t)u.w * 64 + lane];
    a1x += ((float)t0.x + (float)t1.x) + ((float)t2.x + (float)t3.x);
    a1y += ((float)t0.y + (float)t1.y) + ((float)t2.y + (float)t3.y);
    a1z += ((float)t0.z + (float)t1.z) + ((float)t2.z + (float)t3.z);
    a1w += ((float)t0.w + (float)t1.w) + ((float)t2.w + (float)t3.w);
  }
  for (; j0 < c0; ++j0) {
    half4 tv = h[(size_t)cl0[j0] * 64 + lane];
    a0x += (float)tv.x; a0y += (float)tv.y; a0z += (float)tv.z; a0w += (float)tv.w;
  }
  for (; j1 < c1; ++j1) {
    half4 tv = h[(size_t)cl1[j1] * 64 + lane];
    a1x += (float)tv.x; a1y += (float)tv.y; a1z += (float)tv.z; a1w += (float)tv.w;
  }
  float d0 = dinv[w0], d1 = dinv[w1];
  half4 o0, o1;
  o0.x = (_Float16)(a0x * d0); o0.y = (_Float16)(a0y * d0);
  o0.z = (_Float16)(a0z * d0); o0.w = (_Float16)(a0w * d0);
  o1.x = (_Float16)(a1x * d1); o1.y = (_Float16)(a1y * d1);
  o1.z = (_Float16)(a1z * d1); o1.w = (_Float16)(a1w * d1);
  out[(size_t)w0 * 64 + lane] = o0;
  out[(size_t)w1 * 64 + lane] = o1;
}

// ---------- MFMA fp16 hi/lo-weight GEMM, DMA LDS staging ----------
// 1D grid 784, XCD-aware decode: the two col-blocks of the same 128 rows get
// blockIdx differing by exactly 8 -> same XCD under %8 round-robin -> A-tile
// L2 reuse. r = (b>>4)*8 + (b&7), c = (b>>3)&1.
__global__ __launch_bounds__(256) void k_mm(const _Float16* __restrict__ A,
                                            const _Float16* __restrict__ Bh,
                                            const _Float16* __restrict__ Bl,
                                            const float* __restrict__ bias,
                                            _Float16* __restrict__ C,
                                            const float* __restrict__ dinv,
                                            const int* __restrict__ batch,
                                            unsigned* __restrict__ gpool,
                                            int M, int K, int Nc, int mode) {
  __shared__ __align__(16) _Float16 Alds[128 * 64];   // 16 KB
  __shared__ __align__(16) _Float16 Bhl[128 * 64];    // 16 KB
  __shared__ __align__(16) _Float16 Bll[128 * 64];    // 16 KB
  int bid = blockIdx.x;
  int rblk = (bid >> 4) * 8 + (bid & 7);
  int cblk = (bid >> 3) & 1;
  if (rblk * 128 >= M) return;
  int rowBase = rblk * 128;
  int colBase = cblk * 128;
  int t = threadIdx.x;
  int wave = t >> 6, lane = t & 63;
  int wm = wave & 1, wn = wave >> 1;
  int lm = lane & 15;
  int q  = lane >> 4;

  int srl = wave * 32 + (lane >> 3);
  int sj  = lane & 7;
  int ssw = lane >> 3;
  int gseg = sj ^ ssw;

  f32x4 acc[4][4];
#pragma unroll
  for (int i = 0; i < 4; ++i)
#pragma unroll
    for (int j = 0; j < 4; ++j) acc[i][j] = (f32x4){0.f, 0.f, 0.f, 0.f};

  int nit = K >> 6;
  for (int it = 0; it < nit; ++it) {
    __syncthreads();
#pragma unroll
    for (int c = 0; c < 4; ++c) {
      int rl = srl + c * 8;
      int ga = rowBase + rl; if (ga > M - 1) ga = M - 1;
      int gb = colBase + rl;
      unsigned off = (unsigned)it * 64 + gseg * 8;
      int ldst = (wave * 32 + c * 8) * 64 + lane * 8;
      gl_lds16(A  + (size_t)ga * K + off, Alds + ldst);
      gl_lds16(Bh + (size_t)gb * K + off, Bhl + ldst);
      gl_lds16(Bl + (size_t)gb * K + off, Bll + ldst);
    }
    __syncthreads();

#pragma unroll
    for (int s2 = 0; s2 < 2; ++s2) {
      int slotq = ((s2 << 2) | q);
      f16x8 vbh[4], vbl[4];
#pragma unroll
      for (int ni = 0; ni < 4; ++ni) {
        int rB = wn * 64 + ni * 16 + lm;
        int slot = slotq ^ (lm & 7);
        vbh[ni] = *(const f16x8*)(Bhl + rB * 64 + slot * 8);
        vbl[ni] = *(const f16x8*)(Bll + rB * 64 + slot * 8);
      }
#pragma unroll
      for (int mi = 0; mi < 4; ++mi) {
        int rA = wm * 64 + mi * 16 + lm;
        int slot = slotq ^ (lm & 7);
        f16x8 va = *(const f16x8*)(Alds + rA * 64 + slot * 8);
#pragma unroll
        for (int ni = 0; ni < 4; ++ni) {
          acc[mi][ni] = __builtin_amdgcn_mfma_f32_16x16x32_f16(va, vbh[ni], acc[mi][ni], 0, 0, 0);
          acc[mi][ni] = __builtin_amdgcn_mfma_f32_16x16x32_f16(va, vbl[ni], acc[mi][ni], 0, 0, 0);
        }
      }
    }
  }

  int rowOff = (lane >> 4) * 4;
  if (mode == 2) {
    __syncthreads();
    unsigned* ldsPool = (unsigned*)Alds;
    for (int i = t; i < 4 * 256; i += 256) ldsPool[i] = 0u;
    __syncthreads();
    int b0 = batch[rowBase];
#pragma unroll
    for (int mi = 0; mi < 4; ++mi) {
#pragma unroll
      for (int ni = 0; ni < 4; ++ni) {
        int gc = colBase + wn * 64 + ni * 16 + lm;
        float bsv = bias[gc];
#pragma unroll
        for (int r = 0; r < 4; ++r) {
          int gr = rowBase + wm * 64 + mi * 16 + rowOff + r;
          if (gr < M) {
            float v = acc[mi][ni][r] + bsv;
            int idx = batch[gr] - b0;
            if (idx < 0) idx = 0;
            if (idx > 3) idx = 3;
            atomicMax(&ldsPool[idx * 256 + gc], f2mono(v));
          }
        }
      }
    }
    __syncthreads();
#pragma unroll
    for (int s4 = 0; s4 < 4; ++s4) {
      unsigned mv = ldsPool[s4 * 256 + t];
      int gb = b0 + s4;
      if (mv && gb < NG) atomicMax(&gpool[gb * 256 + t], mv);
    }
  } else {
#pragma unroll
    for (int mi = 0; mi < 4; ++mi) {
#pragma unroll
      for (int ni = 0; ni < 4; ++ni) {
        int gc = colBase + wn * 64 + ni * 16 + lm;
        float bsv = bias[gc];
#pragma unroll
        for (int r = 0; r < 4; ++r) {
          int gr = rowBase + wm * 64 + mi * 16 + rowOff + r;
          if (gr < M) {
            float v = fmaxf(acc[mi][ni][r] + bsv, 0.0f);
            C[(size_t)gr * Nc + gc] = (_Float16)(v * dinv[gr]);
          }
        }
      }
    }
  }
}

// ---------- dense head ----------
__global__ __launch_bounds__(256) void k_head(const unsigned* __restrict__ g,
                                              const float* __restrict__ Wl2, const float* __restrict__ bl2,
                                              const float* __restrict__ Wl3, const float* __restrict__ bl3,
                                              const float* __restrict__ Wl, const float* __restrict__ bl,
                                              float* __restrict__ out) {
  __shared__ float s0[256];
  __shared__ float s1[128];
  __shared__ float s2[128];
  int b = blockIdx.x, t = threadIdx.x;
  s0[t] = mono2f(g[b * 256 + t]);
  __syncthreads();
  if (t < 128) {
    float acc = bl2[t];
    for (int k = 0; k < 256; ++k) acc += s0[k] * Wl2[k * 128 + t];
    s1[t] = fmaxf(acc, 0.0f);
  }
  __syncthreads();
  if (t < 128) {
    float acc = bl3[t];
    for (int k = 0; k < 128; ++k) acc += s1[k] * Wl3[k * 128 + t];
    s2[t] = fmaxf(acc, 0.0f);
  }
  __syncthreads();
  if (t < 10) {
    float acc = bl[t];
    for (int k = 0; k < 128; ++k) acc += s2[k] * Wl[k * 10 + t];
    out[b * 10 + t] = acc;
  }
}

extern "C" void kernel_launch(void* const* d_in, const int* in_sizes, int n_in,
                              void* d_out, int out_size, void* d_ws, size_t ws_size,
                              hipStream_t stream) {
  const float* x   = (const float*)d_in[0];
  const int* eidx  = (const int*)d_in[1];
  const int* batch = (const int*)d_in[2];
  const float* W1 = (const float*)d_in[3];   const float* b1 = (const float*)d_in[4];
  const float* W2 = (const float*)d_in[5];   const float* b2 = (const float*)d_in[6];
  const float* W3 = (const float*)d_in[7];   const float* b3 = (const float*)d_in[8];
  const float* W4 = (const float*)d_in[9];   const float* b4 = (const float*)d_in[10];
  const float* Wl2 = (const float*)d_in[11]; const float* bl2 = (const float*)d_in[12];
  const float* Wl3 = (const float*)d_in[13]; const float* bl3 = (const float*)d_in[14];
  const float* Wl  = (const float*)d_in[15]; const float* bl  = (const float*)d_in[16];
  float* out = (float*)d_out;

  // ---- workspace carve ----
  _Float16* bufA = (_Float16*)d_ws;                                // NN*256 fp16
  _Float16* bufB = bufA + (size_t)NN * 256;                        // NN*256 fp16
  int* cnt  = (int*)(bufB + (size_t)NN * 256);                     // NN
  float* dinv = (float*)(cnt + NN);                                // NN
  u16* col  = (u16*)(dinv + NN);                                   // NN*CAP ushort
  unsigned* g = (unsigned*)(col + (size_t)NN * CAP);               // NG*256
  _Float16* W2h = (_Float16*)(g + NG * 256);                       // 256*128
  _Float16* W2l = W2h + 256 * 128;
  _Float16* W3h = W2l + 256 * 128;                                 // 256*256
  _Float16* W3l = W3h + 256 * 256;
  _Float16* W4h = W3l + 256 * 256;
  _Float16* W4l = W4h + 256 * 256;
  float* xs = (float*)bufA;        // NN*9 fp32, dead before k_gemm9 writes bufA
  float* agg9out = (float*)bufB;   // NN*9 fp32, dead before k_agg128 writes bufB

  const int* src = eidx;
  const int* dst = eidx + NE;

  hipMemsetAsync(cnt, 0, NN * sizeof(int), stream);

  k_count<<<(NE + 255) / 256, 256, 0, stream>>>(src, dst, cnt, col);
  k_dinv<<<(NN + 255) / 256, 256, 0, stream>>>(cnt, dinv, x, xs, g);

  k_splitw3<<<(128 * 256 + 2 * 256 * 256 + 255) / 256, 256, 0, stream>>>(
      W2, W3, W4, W2h, W2l, W3h, W3l, W4h, W4l);

  // layer 1: agg 9-dim fp32, GEMM 9->128 (+relu, *dinv, fp16 out to bufA)
  k_agg9<<<(NN + 15) / 16, 256, 0, stream>>>(xs, agg9out, cnt, col, dinv);
  k_gemm9<<<NN / 2, 256, 0, stream>>>(agg9out, W1, b1, dinv, bufA);

  int aggGrid = ((NN / 2) * 64 + 255) / 256;   // two nodes per wave
  const int mmGrid = 784;                      // 392 row-blocks x 2 col-blocks, XCD-paired

  // layer 2: gather 128-dim bufA->bufB, MFMA GEMM 128->256 bufB->bufA
  k_agg128<<<aggGrid, 256, 0, stream>>>((const half2v*)bufA, (half2v*)bufB, cnt, col, dinv);
  k_mm<<<mmGrid, 256, 0, stream>>>(bufB, W2h, W2l, b2, bufA, dinv, batch, g, NN, 128, 256, 1);

  // layer 3: gather 256-dim bufA->bufB, GEMM bufB->bufA
  k_agg256<<<aggGrid, 256, 0, stream>>>((const half4*)bufA, (half4*)bufB, cnt, col, dinv);
  k_mm<<<mmGrid, 256, 0, stream>>>(bufB, W3h, W3l, b3, bufA, dinv, batch, g, NN, 256, 256, 1);

  // layer 4: gather 256-dim bufA->bufB, GEMM + fused max-pool (no C write)
  k_agg256<<<aggGrid, 256, 0, stream>>>((const half4*)bufA, (half4*)bufB, cnt, col, dinv);
  k_mm<<<mmGrid, 256, 0, stream>>>(bufB, W4h, W4l, b4, bufA, dinv, batch, g, NN, 256, 256, 2);

  // head
  k_head<<<NG, 256, 0, stream>>>(g, Wl2, bl2, Wl3, bl3, Wl, bl, out);
}